// Round 14
// baseline (426.115 us; speedup 1.0000x reference)
//
#include <hip/hip_runtime.h>
#include <math.h>

#define NN 50000
#define NE 800000
#define DIN 32
#define D 128
#define NL 3
#define NG 64
#define LN_EPS 1e-5f
#define SCAN_BLOCKS 196   // ceil(NN/256)

// fused-prep grid layout
#define PR_T   48             // transpose: 4 regions x 3 layers x 4 tiles(64x64)
#define PR_W2P (PR_T + 192)   // w2p
#define PR_B2P (PR_W2P + 2)   // b2p (384 threads)
#define PR_WIN (PR_B2P + 16)  // winT
#define PR_CNT (PR_WIN + 32)  // count
#define PR_TOTAL (PR_CNT + NE / 256)   // + hist: 3415

#define NBLK_IP 782           // input_proj blocks in fused scatter+inproj

typedef unsigned short u16;
typedef __bf16 bf16x8 __attribute__((ext_vector_type(8)));
typedef float f32x4 __attribute__((ext_vector_type(4)));

// exact gelu (erf) — REQUIRED on the hidden path: replacing it with the
// tanh-approx tripled final absmax (round-5: 0.0625 -> 0.1875, fail).
__device__ __forceinline__ float gelu_f(float x) {
    return 0.5f * x * (1.0f + erff(x * 0.70710678118654752f));
}

// tanh-approx gelu: ONLY for edge messages (baseline-proven at absmax 0.0625).
__device__ __forceinline__ float gelu_fast(float x) {
    float u = x * x;
    float z = x * fmaf(-0.1029432f, u, -2.3022082f);
    float e = __builtin_amdgcn_exp2f(z);
    float s = __builtin_amdgcn_rcpf(1.0f + e);
    return x * s;
}

__device__ __forceinline__ u16 f2bf(float x) {
    unsigned int u = __float_as_uint(x);
    u += 0x7fffu + ((u >> 16) & 1u);
    return (u16)(u >> 16);
}

// ---------------- single-pass CSR scan ----------------
__global__ __launch_bounds__(256) void scan_emit_kernel(
    const int* __restrict__ hist, int* __restrict__ row_ptr)
{
    __shared__ int sc[256];
    __shared__ int red[256];
    const int t = threadIdx.x;
    const int blk = blockIdx.x;
    const int i = blk * 256 + t;
    int orig = (i < NN) ? hist[i] : 0;
    sc[t] = orig;

    int seg = 0;
    if (t < blk) {
        const int4* hp = (const int4*)(hist + t * 256);
#pragma unroll 8
        for (int m = 0; m < 64; ++m) {
            int4 v = hp[m];
            seg += v.x + v.y + v.z + v.w;
        }
    }
    red[t] = seg;
    __syncthreads();
    for (int off = 128; off > 0; off >>= 1) {
        if (t < off) red[t] += red[t + off];
        __syncthreads();
    }
    for (int off = 1; off < 256; off <<= 1) {
        int v = (t >= off) ? sc[t - off] : 0;
        __syncthreads();
        sc[t] += v;
        __syncthreads();
    }
    if (i < NN) row_ptr[i] = sc[t] - orig + red[0];
    if (i == 0) row_ptr[NN] = NE;
}

// ---------------- fused prep ----------------
__global__ __launch_bounds__(256) void prep_kernel(
    const float* __restrict__ eW1, const float* __restrict__ uW1,
    const float* __restrict__ uW2, const float* __restrict__ eW2,
    const float* __restrict__ eb2, const float* __restrict__ Wi,
    const int* __restrict__ batch, const int* __restrict__ dst,
    u16* __restrict__ PWT, u16* __restrict__ NW1T, u16* __restrict__ uW2T,
    float* __restrict__ nb2p, u16* __restrict__ WinT,
    float* __restrict__ counts, int* __restrict__ hist,
    int* __restrict__ rank)
{
    __shared__ __attribute__((aligned(16))) float ldsF[64 * 65];  // 16.6 KB
    const int blk = blockIdx.x;
    const int tid = threadIdx.x;
    if (blk < PR_T) {
        const int region = blk / 12;
        const int rl = blk - region * 12;
        const int l = rl >> 2;
        const int tile = rl & 3;
        const int k0 = (tile >> 1) * 64, n0 = (tile & 1) * 64;
        const float* srcp; u16* dstp; int dstRS;
        if (region == 0)      { srcp = eW1 + (size_t)l * 257 * 128;         dstp = PWT  + (size_t)l * 32768;         dstRS = 128; }
        else if (region == 1) { srcp = eW1 + (size_t)l * 257 * 128 + 16384; dstp = PWT  + (size_t)l * 32768 + 16384; dstRS = 128; }
        else if (region == 2) { srcp = uW1 + (size_t)l * 32768;             dstp = NW1T + (size_t)l * 32768;         dstRS = 256; }
        else                  { srcp = uW2 + (size_t)l * 16384;             dstp = uW2T + (size_t)l * 16384;         dstRS = 128; }
        const int rr = tid >> 6, cc = tid & 63;
#pragma unroll
        for (int it = 0; it < 16; ++it) {
            int row = it * 4 + rr;
            ldsF[row * 65 + cc] = srcp[(size_t)(k0 + row) * 128 + n0 + cc];
        }
        __syncthreads();
#pragma unroll
        for (int it = 0; it < 16; ++it) {
            int row = it * 4 + rr;
            dstp[(size_t)(n0 + row) * dstRS + k0 + cc] = f2bf(ldsF[cc * 65 + row]);
        }
    } else if (blk < PR_W2P) {
        int i = (blk - PR_T) * 256 + tid;
        int l = i / 16384;
        int r = i - l * 16384;
        int k = r >> 7, n = r & 127;
        const float* w2row = eW2 + (size_t)l * 16384 + k * 128;
        const float* u1col = uW1 + (size_t)l * 32768 + 128 * 128 + n;
        float s = 0.f;
#pragma unroll 4
        for (int j = 0; j < 128; ++j) s = fmaf(w2row[j], u1col[j * 128], s);
        NW1T[(size_t)l * 32768 + n * 256 + 128 + k] = f2bf(s);
    } else if (blk < PR_B2P) {
        int i = (blk - PR_W2P) * 256 + tid;
        if (i < NL * 128) {
            int l = i >> 7, n = i & 127;
            const float* b2r = eb2 + l * 128;
            const float* u1col = uW1 + (size_t)l * 32768 + 128 * 128 + n;
            float s = 0.f;
#pragma unroll 4
            for (int j = 0; j < 128; ++j) s = fmaf(b2r[j], u1col[j * 128], s);
            nb2p[l * 128 + n] = s;
        }
    } else if (blk < PR_WIN) {
        int i = (blk - PR_B2P) * 256 + tid;
        int n = i >> 5, k = i & 31;
        WinT[n * 32 + k] = f2bf(Wi[k * 128 + n]);
    } else if (blk < PR_CNT) {
        float* s_counts = ldsF;
        if (tid < NG) s_counts[tid] = 0.f;
        __syncthreads();
        int t = (blk - PR_WIN) * 256 + tid;
        const int chunk = (NN + 8191) / 8192;
        int beg = t * chunk, end = beg + chunk;
        if (end > NN) end = NN;
        if (beg < NN) {
            int cur = batch[beg];
            float cnt = 0.f;
            for (int i2 = beg; i2 < end; ++i2) {
                int b2 = batch[i2];
                if (b2 != cur) { atomicAdd(&s_counts[cur], cnt); cur = b2; cnt = 0.f; }
                cnt += 1.f;
            }
            atomicAdd(&s_counts[cur], cnt);
        }
        __syncthreads();
        if (tid < NG) {
            float v = s_counts[tid];
            if (v != 0.f) atomicAdd(&counts[tid], v);
        }
    } else {
        int e = (blk - PR_CNT) * 256 + tid;
        rank[e] = atomicAdd(&hist[dst[e]], 1);   // rank = old count
    }
}

// ---------------- fused scatter + input_proj -------------------------------
__global__ __launch_bounds__(256) void scatter_inproj_kernel(
    const int* __restrict__ src, const int* __restrict__ dstp,
    const float* __restrict__ ew, const int* __restrict__ rank,
    const int* __restrict__ row_ptr, int2* __restrict__ sEdge,
    const float* __restrict__ X, const u16* __restrict__ WinT,
    const float* __restrict__ b, u16* __restrict__ hbf,
    const u16* __restrict__ PWT, u16* __restrict__ P)
{
    __shared__ __attribute__((aligned(16))) u16 lds[64 * 264];  // 33792 B
    const int blk = blockIdx.x;
    const int tid = threadIdx.x;

    if (blk >= NBLK_IP) {   // ---- scatter region (no atomics) ----
        int e = (blk - NBLK_IP) * 256 + tid;
        int d = dstp[e];
        int pos = row_ptr[d] + rank[e];
        int2 v;
        v.x = src[e] << 9;            // row offset in bytes into P
        v.y = __float_as_int(ew[e]);
        sEdge[pos] = v;
        return;
    }

    // ---- input_proj region ----
    u16* sO  = lds;              // 64 x 136 bf16 hidden stage
    u16* sXb = lds + 64 * 136;   // 64 x 72 bf16 X stage: [hi(32) | lo(32) | pad]
    const int n0 = blk * 64;
    const int e = tid >> 2, q = tid & 3;

    {   // stage X -> hi/lo bf16 split (x = hi + lo recovers f32 precision)
        const int n = n0 + e;
        unsigned hiw[4], low[4];
        if (n < NN) {
            const float4* xr = (const float4*)(X + (size_t)n * DIN + q * 8);
            float vv[8];
            *(float4*)(vv) = xr[0];
            *(float4*)(vv + 4) = xr[1];
#pragma unroll
            for (int j = 0; j < 4; ++j) {
                u16 h0 = f2bf(vv[2 * j]), h1 = f2bf(vv[2 * j + 1]);
                float f0 = __uint_as_float((unsigned)h0 << 16);
                float f1 = __uint_as_float((unsigned)h1 << 16);
                u16 l0 = f2bf(vv[2 * j] - f0), l1 = f2bf(vv[2 * j + 1] - f1);
                hiw[j] = (unsigned)h0 | ((unsigned)h1 << 16);
                low[j] = (unsigned)l0 | ((unsigned)l1 << 16);
            }
        } else {
#pragma unroll
            for (int j = 0; j < 4; ++j) { hiw[j] = 0u; low[j] = 0u; }
        }
        *(uint4*)(sXb + e * 72 + q * 8)      = *(uint4*)hiw;
        *(uint4*)(sXb + e * 72 + 32 + q * 8) = *(uint4*)low;
    }
    __syncthreads();

    const int lane = tid & 63;
    const int l15 = lane & 15;
    const int quad = lane >> 4;
    const int w = tid >> 6;          // wave id: owns cols w*32..w*32+31

    {   // in-proj MFMA (2 accumulating K-steps: hi then lo), bias + exact gelu
        f32x4 acc1[4][2];
#pragma unroll
        for (int mt = 0; mt < 4; ++mt)
#pragma unroll
            for (int nt = 0; nt < 2; ++nt) acc1[mt][nt] = (f32x4){0.f, 0.f, 0.f, 0.f};

        bf16x8 bfw[2];
#pragma unroll
        for (int nt = 0; nt < 2; ++nt)
            bfw[nt] = *(const bf16x8*)(WinT + (size_t)(w * 32 + nt * 16 + l15) * 32 + quad * 8);
#pragma unroll
        for (int mt = 0; mt < 4; ++mt) {
            bf16x8 ah = *(const bf16x8*)(sXb + (mt * 16 + l15) * 72 + quad * 8);
            bf16x8 al = *(const bf16x8*)(sXb + (mt * 16 + l15) * 72 + 32 + quad * 8);
            acc1[mt][0] = __builtin_amdgcn_mfma_f32_16x16x32_bf16(ah, bfw[0], acc1[mt][0], 0, 0, 0);
            acc1[mt][0] = __builtin_amdgcn_mfma_f32_16x16x32_bf16(al, bfw[0], acc1[mt][0], 0, 0, 0);
            acc1[mt][1] = __builtin_amdgcn_mfma_f32_16x16x32_bf16(ah, bfw[1], acc1[mt][1], 0, 0, 0);
            acc1[mt][1] = __builtin_amdgcn_mfma_f32_16x16x32_bf16(al, bfw[1], acc1[mt][1], 0, 0, 0);
        }
#pragma unroll
        for (int mt = 0; mt < 4; ++mt)
#pragma unroll
            for (int nt = 0; nt < 2; ++nt) {
                const int col = w * 32 + nt * 16 + l15;
                const float bb = b[col];
#pragma unroll
                for (int r = 0; r < 4; ++r) {
                    const int row = mt * 16 + quad * 4 + r;
                    sO[row * 136 + col] = f2bf(gelu_f(acc1[mt][nt][r] + bb));
                }
            }
    }
    __syncthreads();   // sO complete, visible to all waves

    // hbf store
    {
        const int n = n0 + e;
        if (n < NN) {
            uint4* hp = (uint4*)(hbf + (size_t)n * D);
            const u16* so = sO + e * 136;
#pragma unroll
            for (int c = 0; c < 4; ++c) hp[q + c * 4] = *(const uint4*)(so + (q + c * 4) * 8);
        }
    }

    // layer-0 P-GEMM: P[n][0:256] = hidden[n] @ [W1a|W1b]
    const int nbase4 = w * 64;

    f32x4 accp[4][4];
#pragma unroll
    for (int mt = 0; mt < 4; ++mt)
#pragma unroll
        for (int nt = 0; nt < 4; ++nt) accp[mt][nt] = (f32x4){0.f, 0.f, 0.f, 0.f};

#pragma unroll
    for (int kb = 0; kb < 128; kb += 32) {
        bf16x8 bf[4];
#pragma unroll
        for (int nt = 0; nt < 4; ++nt)
            bf[nt] = *(const bf16x8*)(PWT + (size_t)(nbase4 + nt * 16 + l15) * 128 + quad * 8 + kb);
#pragma unroll
        for (int mt = 0; mt < 4; ++mt) {
            bf16x8 af = *(const bf16x8*)(sO + (mt * 16 + l15) * 136 + quad * 8 + kb);
#pragma unroll
            for (int nt = 0; nt < 4; ++nt)
                accp[mt][nt] = __builtin_amdgcn_mfma_f32_16x16x32_bf16(af, bf[nt], accp[mt][nt], 0, 0, 0);
        }
    }
    __syncthreads();   // all sO reads done -> reuse as sP

    u16* sP = lds;     // 64 x 264 u16
#pragma unroll
    for (int mt = 0; mt < 4; ++mt)
#pragma unroll
        for (int nt = 0; nt < 4; ++nt) {
            const int col = nbase4 + nt * 16 + l15;
#pragma unroll
            for (int r = 0; r < 4; ++r)
                sP[(mt * 16 + quad * 4 + r) * 264 + col] = f2bf(accp[mt][nt][r]);
        }
    __syncthreads();
    {
        const int n = n0 + e;
        if (n < NN) {
            uint4* op = (uint4*)(P + (size_t)n * 256);
            const u16* sp = sP + e * 264;
#pragma unroll
            for (int c = 0; c < 8; ++c) op[q + c * 4] = *(const uint4*)(sp + (q + c * 4) * 8);
        }
    }
}

// CSR edge pass: one wave per dst node, lane owns 2 cols. Zero atomics.
// Round-14: 4-way split accumulators + 8-deep gather pipeline. The old
// 2-chain version serialized 16 adds + 2 quarter-rate transcendentals per
// edge per chain (VALUBusy 64%); 4 independent chains per column interleave
// gelu work through the TRANS pipe. f32 regrouping only (well below bf16
// noise); deterministic given sEdge.
__global__ __launch_bounds__(256) void edge_csr_kernel(
    const u16* __restrict__ P, const int2* __restrict__ sEdge,
    const int* __restrict__ row_ptr,
    const float* __restrict__ W1last, const float* __restrict__ b1,
    u16* __restrict__ Sbf)
{
    const int n = (blockIdx.x * 256 + threadIdx.x) >> 6;
    if (n >= NN) return;
    const int lane = threadIdx.x & 63;
    const int c2 = lane * 2;
    const unsigned laneoff = (unsigned)(c2 * 2);   // byte offset of this lane's dword in a P row
    const char* Pb = (const char*)P;

    const float wl0 = W1last[c2], wl1 = W1last[c2 + 1];
    unsigned p2 = *(const unsigned*)(Pb + ((unsigned)n * 512u + 256u + laneoff));
    const float t20 = __uint_as_float(p2 << 16) + b1[c2];
    const float t21 = __uint_as_float(p2 & 0xffff0000u) + b1[c2 + 1];

    float s0[4] = {0.f, 0.f, 0.f, 0.f};
    float s1[4] = {0.f, 0.f, 0.f, 0.f};
    const int beg = row_ptr[n];
    const int m = row_ptr[n + 1] - beg;
    const int2* ep = sEdge + beg;
    int i = 0;
    for (; i + 7 < m; i += 8) {            // 8 gathers in flight, 4 acc chains
        int2 qv[8];
#pragma unroll
        for (int j = 0; j < 8; ++j) qv[j] = ep[i + j];
        unsigned pv[8];
#pragma unroll
        for (int j = 0; j < 8; ++j)
            pv[j] = *(const unsigned*)(Pb + ((unsigned)qv[j].x + laneoff));
#pragma unroll
        for (int j = 0; j < 8; ++j) {
            float wj = __int_as_float(qv[j].y);
            s0[j & 3] += gelu_fast(fmaf(wj, wl0, __uint_as_float(pv[j] << 16) + t20));
            s1[j & 3] += gelu_fast(fmaf(wj, wl1, __uint_as_float(pv[j] & 0xffff0000u) + t21));
        }
    }
    for (; i < m; ++i) {
        int2 q0 = ep[i];
        unsigned pa = *(const unsigned*)(Pb + ((unsigned)q0.x + laneoff));
        float w0 = __int_as_float(q0.y);
        s0[i & 3] += gelu_fast(fmaf(w0, wl0, __uint_as_float(pa << 16) + t20));
        s1[i & 3] += gelu_fast(fmaf(w0, wl1, __uint_as_float(pa & 0xffff0000u) + t21));
    }
    float a0 = (s0[0] + s0[1]) + (s0[2] + s0[3]);
    float a1 = (s1[0] + s1[1]) + (s1[2] + s1[3]);
    unsigned pk = (unsigned)f2bf(a0) | ((unsigned)f2bf(a1) << 16);
    *(unsigned*)(Sbf + (size_t)n * D + c2) = pk;
}

// Node update on MFMA + residual + LayerNorm; two-pass next-layer P-GEMM
// (round-11: keeps regs under the (256,4) cap -> single co-residency round);
// fused pooling accumulation on the last layer (write_f32).
__global__ __launch_bounds__(256, 4) void node_mfma_kernel(
    const u16* __restrict__ hbf, const u16* __restrict__ Sbf,
    const int* __restrict__ hist,
    const u16* __restrict__ NW1T, const float* __restrict__ ub1,
    const float* __restrict__ nb2p,
    const u16* __restrict__ W2T, const float* __restrict__ b2,
    const float* __restrict__ gamma, const float* __restrict__ beta,
    float* __restrict__ hidden_out, u16* __restrict__ hbf_out,
    const u16* __restrict__ PWTnext, u16* __restrict__ Pout, int write_f32,
    const int* __restrict__ batch, float* __restrict__ pooled)
{
    __shared__ __attribute__((aligned(16))) u16 ldsA[64 * 136 * 2];  // 34816 B
    __shared__ float s_cnt[64];
    __shared__ int s_b[64];
    u16* sHa = ldsA;               // 64x136: hbf rows (live until residual)
    u16* sSb = ldsA + 64 * 136;    // 64x136: Sbf rows, then H1 (gelu out)
    float* sR = (float*)ldsA;      // 64x132 f32 LN buffer (reuses all)
    const int tid = threadIdx.x;
    const int n0 = blockIdx.x * 64;

    if (tid < 64) {
        int n = n0 + tid;
        s_b[tid] = (write_f32 && n < NN) ? batch[n] : -1;
        if (n >= NN) n = NN - 1;
        s_cnt[tid] = (float)hist[n];
    }
    {
        const int e = tid >> 2, q = tid & 3;
        int n = n0 + e; if (n >= NN) n = NN - 1;
        const uint4* hs = (const uint4*)(hbf + (size_t)n * D);
        const uint4* ss = (const uint4*)(Sbf + (size_t)n * D);
#pragma unroll
        for (int j = 0; j < 4; ++j) {          // full 128-u16 row per buffer
            const int c = q * 4 + j;
            *(uint4*)(sHa + e * 136 + c * 8) = hs[c];
            *(uint4*)(sSb + e * 136 + c * 8) = ss[c];
        }
    }
    __syncthreads();

    const int lane = tid & 63;
    const int l15 = lane & 15;
    const int quad = lane >> 4;
    const int nbase = (tid >> 6) * 32;

    f32x4 acc[4][2];
#pragma unroll
    for (int mt = 0; mt < 4; ++mt)
#pragma unroll
        for (int nt = 0; nt < 2; ++nt) acc[mt][nt] = (f32x4){0.f, 0.f, 0.f, 0.f};

    const u16* bp0 = NW1T + (size_t)(nbase + l15) * 256 + quad * 8;
    const u16* bp1 = bp0 + 16 * 256;
#pragma unroll
    for (int kb = 0; kb < 256; kb += 32) {
        bf16x8 bf0 = *(const bf16x8*)(bp0 + kb);
        bf16x8 bf1 = *(const bf16x8*)(bp1 + kb);
        const u16* abase = (kb < 128) ? sHa : sSb;   // compile-time under unroll
        const int kk = kb & 127;
#pragma unroll
        for (int mt = 0; mt < 4; ++mt) {
            bf16x8 af = *(const bf16x8*)(abase + (mt * 16 + l15) * 136 + quad * 8 + kk);
            acc[mt][0] = __builtin_amdgcn_mfma_f32_16x16x32_bf16(af, bf0, acc[mt][0], 0, 0, 0);
            acc[mt][1] = __builtin_amdgcn_mfma_f32_16x16x32_bf16(af, bf1, acc[mt][1], 0, 0, 0);
        }
    }
    __syncthreads();   // all GEMM1 A-reads done; sSb becomes H1

#pragma unroll
    for (int mt = 0; mt < 4; ++mt)
#pragma unroll
        for (int nt = 0; nt < 2; ++nt) {
            const int col = nbase + nt * 16 + l15;
            const float bb = ub1[col];
            const float bp = nb2p[col];
#pragma unroll
            for (int r = 0; r < 4; ++r) {
                const int row = mt * 16 + quad * 4 + r;
                float v = acc[mt][nt][r] + bb + s_cnt[row] * bp;
                sSb[row * 136 + col] = f2bf(gelu_f(v));
            }
        }
    __syncthreads();

    f32x4 acc2[4][2];
#pragma unroll
    for (int mt = 0; mt < 4; ++mt)
#pragma unroll
        for (int nt = 0; nt < 2; ++nt) acc2[mt][nt] = (f32x4){0.f, 0.f, 0.f, 0.f};

    const u16* cp0 = W2T + (size_t)(nbase + l15) * 128 + quad * 8;
    const u16* cp1 = cp0 + 16 * 128;
#pragma unroll
    for (int kb = 0; kb < 128; kb += 32) {
        bf16x8 bf0 = *(const bf16x8*)(cp0 + kb);
        bf16x8 bf1 = *(const bf16x8*)(cp1 + kb);
#pragma unroll
        for (int mt = 0; mt < 4; ++mt) {
            bf16x8 af = *(const bf16x8*)(sSb + (mt * 16 + l15) * 136 + quad * 8 + kb);
            acc2[mt][0] = __builtin_amdgcn_mfma_f32_16x16x32_bf16(af, bf0, acc2[mt][0], 0, 0, 0);
            acc2[mt][1] = __builtin_amdgcn_mfma_f32_16x16x32_bf16(af, bf1, acc2[mt][1], 0, 0, 0);
        }
    }

    // bias + residual from LDS (sHa still intact)
#pragma unroll
    for (int mt = 0; mt < 4; ++mt)
#pragma unroll
        for (int nt = 0; nt < 2; ++nt) {
            const int col = nbase + nt * 16 + l15;
            const float bb = b2[col];
#pragma unroll
            for (int r = 0; r < 4; ++r) {
                const int row = mt * 16 + quad * 4 + r;
                float h = __uint_as_float((unsigned)sHa[row * 136 + col] << 16);
                acc2[mt][nt][r] += bb + h;
            }
        }
    __syncthreads();   // all reads of ldsA done; overwrite with f32 sR

#pragma unroll
    for (int mt = 0; mt < 4; ++mt)
#pragma unroll
        for (int nt = 0; nt < 2; ++nt) {
            const int col = nbase + nt * 16 + l15;
#pragma unroll
            for (int r = 0; r < 4; ++r)
                sR[(mt * 16 + quad * 4 + r) * 132 + col] = acc2[mt][nt][r];
        }
    __syncthreads();

    // LayerNorm: 4 lanes per row (same wave). bf16 written in place (safe:
    // data dependence on rs orders all row reads before any store).
    {
        const int e = tid >> 2, t4 = tid & 3;
        float* rr = sR + e * 132 + t4 * 32;
        float s1 = 0.f, s2 = 0.f;
        float4 v[8];
#pragma unroll
        for (int i = 0; i < 8; ++i) {
            v[i] = *(const float4*)(rr + i * 4);
            s1 += v[i].x + v[i].y + v[i].z + v[i].w;
            s2 += v[i].x * v[i].x + v[i].y * v[i].y + v[i].z * v[i].z + v[i].w * v[i].w;
        }
        s1 += __shfl_xor(s1, 1); s2 += __shfl_xor(s2, 1);
        s1 += __shfl_xor(s1, 2); s2 += __shfl_xor(s2, 2);
        const float mean = s1 * (1.f / 128.f);
        const float var = s2 * (1.f / 128.f) - mean * mean;
        const float rs = rsqrtf(var + LN_EPS);
        u16* hrow = (u16*)(sR + e * 132);   // bf16 row, stride 264 u16
#pragma unroll
        for (int i = 0; i < 8; ++i) {
            const float4 g = *(const float4*)(gamma + t4 * 32 + i * 4);
            const float4 be = *(const float4*)(beta + t4 * 32 + i * 4);
            float4 o;
            o.x = (v[i].x - mean) * rs * g.x + be.x;
            o.y = (v[i].y - mean) * rs * g.y + be.y;
            o.z = (v[i].z - mean) * rs * g.z + be.z;
            o.w = (v[i].w - mean) * rs * g.w + be.w;
            if (write_f32) {
                *(float4*)(rr + i * 4) = o;
            } else {
                uint2 pk;
                pk.x = (unsigned)f2bf(o.x) | ((unsigned)f2bf(o.y) << 16);
                pk.y = (unsigned)f2bf(o.z) | ((unsigned)f2bf(o.w) << 16);
                *(uint2*)(hrow + t4 * 32 + i * 4) = pk;
            }
        }
    }

    if (write_f32) {
        __syncthreads();   // pooled reads cross-wave rows
        {
            const int e = tid >> 2, q = tid & 3;
            const int n = n0 + e;
            if (n < NN) {
                float4* op = (float4*)(hidden_out + (size_t)n * D);
                const float* sr = sR + e * 132;
#pragma unroll
                for (int c = 0; c < 8; ++c) op[q + c * 4] = *(const float4*)(sr + (q + c * 4) * 4);
            }
        }
        {
            const int col = tid & 127, half = tid >> 7;
            const int base = half * 32;
            int cur = s_b[base];
            float acc_p = 0.f;
            for (int i = 0; i < 32; ++i) {
                int b = s_b[base + i];
                if (b < 0) break;
                if (b != cur) { atomicAdd(&pooled[cur * D + col], acc_p); cur = b; acc_p = 0.f; }
                acc_p += sR[(base + i) * 132 + col];
            }
            if (cur >= 0) atomicAdd(&pooled[cur * D + col], acc_p);
        }
    } else {
        __syncthreads();   // LN bf16 rows visible to all waves
        {
            const int e = tid >> 2, q = tid & 3;
            const int n = n0 + e;
            if (n < NN) {
                uint4* hp = (uint4*)(hbf_out + (size_t)n * D);
                const u16* sh = (const u16*)(sR + e * 132);
#pragma unroll
                for (int c = 0; c < 4; ++c) hp[q + c * 4] = *(const uint4*)(sh + (q + c * 4) * 8);
            }
        }
        if (PWTnext) {
            // two-pass P-GEMM (accp[4][2] each) keeps regs under the (256,4)
            // cap. sHn = bf16 LN rows, stride 264, cols [0,128).
            const u16* sHn = (const u16*)sR;
            u16* sPx = (u16*)sR;               // staging within sR rows
            const int cbase = (tid >> 6) * 32; // wave's 32-col slice per pass
            f32x4 accp[4][2];

            // ---- pass A: P cols [0,128) -> stage at row*264 + 128 + col ----
#pragma unroll
            for (int mt = 0; mt < 4; ++mt)
#pragma unroll
                for (int nt = 0; nt < 2; ++nt) accp[mt][nt] = (f32x4){0.f, 0.f, 0.f, 0.f};
#pragma unroll
            for (int kb = 0; kb < 128; kb += 32) {
                bf16x8 bf0 = *(const bf16x8*)(PWTnext + (size_t)(cbase + l15) * 128 + quad * 8 + kb);
                bf16x8 bf1 = *(const bf16x8*)(PWTnext + (size_t)(cbase + 16 + l15) * 128 + quad * 8 + kb);
#pragma unroll
                for (int mt = 0; mt < 4; ++mt) {
                    bf16x8 af = *(const bf16x8*)(sHn + (size_t)(mt * 16 + l15) * 264 + quad * 8 + kb);
                    accp[mt][0] = __builtin_amdgcn_mfma_f32_16x16x32_bf16(af, bf0, accp[mt][0], 0, 0, 0);
                    accp[mt][1] = __builtin_amdgcn_mfma_f32_16x16x32_bf16(af, bf1, accp[mt][1], 0, 0, 0);
                }
            }
#pragma unroll
            for (int mt = 0; mt < 4; ++mt)
#pragma unroll
                for (int nt = 0; nt < 2; ++nt) {
                    const int col = cbase + nt * 16 + l15;
#pragma unroll
                    for (int r = 0; r < 4; ++r)
                        sPx[(mt * 16 + quad * 4 + r) * 264 + 128 + col] = f2bf(accp[mt][nt][r]);
                }

            // ---- pass B: P cols [128,256) ----
#pragma unroll
            for (int mt = 0; mt < 4; ++mt)
#pragma unroll
                for (int nt = 0; nt < 2; ++nt) accp[mt][nt] = (f32x4){0.f, 0.f, 0.f, 0.f};
#pragma unroll
            for (int kb = 0; kb < 128; kb += 32) {
                bf16x8 bf0 = *(const bf16x8*)(PWTnext + (size_t)(128 + cbase + l15) * 128 + quad * 8 + kb);
                bf16x8 bf1 = *(const bf16x8*)(PWTnext + (size_t)(128 + cbase + 16 + l15) * 128 + quad * 8 + kb);
#pragma unroll
                for (int mt = 0; mt < 4; ++mt) {
                    bf16x8 af = *(const bf16x8*)(sHn + (size_t)(mt * 16 + l15) * 264 + quad * 8 + kb);
                    accp[mt][0] = __builtin_amdgcn_mfma_f32_16x16x32_bf16(af, bf0, accp[mt][0], 0, 0, 0);
                    accp[mt][1] = __builtin_amdgcn_mfma_f32_16x16x32_bf16(af, bf1, accp[mt][1], 0, 0, 0);
                }
            }
            __syncthreads();   // all sHn reads done -> overwrite cols [0,128)
#pragma unroll
            for (int mt = 0; mt < 4; ++mt)
#pragma unroll
                for (int nt = 0; nt < 2; ++nt) {
                    const int col = cbase + nt * 16 + l15;   // = B col - 128
#pragma unroll
                    for (int r = 0; r < 4; ++r)
                        sPx[(mt * 16 + quad * 4 + r) * 264 + col] = f2bf(accp[mt][nt][r]);
                }
            __syncthreads();
            // coalesced store: P[n][0:128) from +128 tail, P[n][128:256) from +0
            const int e2 = tid >> 2, q2 = tid & 3;
            const int n2 = n0 + e2;
            if (n2 < NN) {
                uint4* op = (uint4*)(Pout + (size_t)n2 * 256);
                const u16* rowp = sPx + e2 * 264;
#pragma unroll
                for (int c = 0; c < 4; ++c)
                    op[q2 + c * 4] = *(const uint4*)(rowp + 128 + (q2 + c * 4) * 8);
#pragma unroll
                for (int c = 0; c < 4; ++c)
                    op[16 + q2 + c * 4] = *(const uint4*)(rowp + (q2 + c * 4) * 8);
            }
        }
    }
}

__global__ __launch_bounds__(256) void pool_div_kernel(
    float* __restrict__ pooled, const float* __restrict__ counts)
{
    int i = blockIdx.x * 256 + threadIdx.x;
    pooled[i] /= fmaxf(counts[i >> 7], 1.0f);
}

extern "C" void kernel_launch(void* const* d_in, const int* in_sizes, int n_in,
                              void* d_out, int out_size, void* d_ws, size_t ws_size,
                              hipStream_t stream) {
    const float* X     = (const float*)d_in[0];
    const int*   eidx  = (const int*)d_in[1];
    const float* ew    = (const float*)d_in[2];
    const int*   batch = (const int*)d_in[3];
    const float* W_in  = (const float*)d_in[5];
    const float* b_in  = (const float*)d_in[6];
    const float* eW1   = (const float*)d_in[7];
    const float* eb1   = (const float*)d_in[8];
    const float* eW2   = (const float*)d_in[9];
    const float* eb2   = (const float*)d_in[10];
    const float* uW1   = (const float*)d_in[11];
    const float* ub1   = (const float*)d_in[12];
    const float* uW2   = (const float*)d_in[13];
    const float* ub2   = (const float*)d_in[14];
    const float* gamma = (const float*)d_in[15];
    const float* beta  = (const float*)d_in[16];

    float* out_hidden = (float*)d_out;
    float* out_pooled = out_hidden + (size_t)NN * D;

    u16*   hbf  = (u16*)d_ws;                                  // N*128 bf16
    u16*   P    = hbf + (size_t)NN * D;                        // N*256 bf16
    u16*   Sbf  = P + (size_t)NN * 256;                        // N*128 bf16
    u16*   PWT  = Sbf + (size_t)NN * D;                        // NL*256*128
    u16*   NW1T = PWT + (size_t)NL * 256 * 128;                // NL*128*256
    u16*   uW2T = NW1T + (size_t)NL * 128 * 256;               // NL*128*128
    float* nb2p = (float*)(uW2T + (size_t)NL * 128 * 128);     // NL*128
    u16*   WinT = (u16*)(nb2p + (size_t)NL * 128);             // 128*32 bf16
    int*   hist    = (int*)(WinT + 128 * 32);
    int*   row_ptr = hist + NN;                                // NN+1 ints
    int2*  sEdge   = (int2*)(row_ptr + NN + 3);                // NE int2 (8B aligned)
    float* counts  = (float*)(sEdge + NE);
    int*   rank    = (int*)(counts + NG);                      // NE ints

    const int* src = eidx;
    const int* dst = eidx + NE;

    hipMemsetAsync(hist, 0, (size_t)NN * sizeof(int), stream);
    hipMemsetAsync(out_pooled, 0, (size_t)NG * D * sizeof(float), stream);
    hipMemsetAsync(counts, 0, (size_t)NG * sizeof(float), stream);

    // fused prep: transpose + w2p + b2p + winT + count + hist(+rank)
    prep_kernel<<<PR_TOTAL, 256, 0, stream>>>(
        eW1, uW1, uW2, eW2, eb2, W_in, batch, dst,
        PWT, NW1T, uW2T, nb2p, WinT, counts, hist, rank);

    // single-pass scan (replaces bsum + bscan + emit)
    scan_emit_kernel<<<SCAN_BLOCKS, 256, 0, stream>>>(hist, row_ptr);

    // fused scatter + input_proj (scatter is atomic-free via rank)
    scatter_inproj_kernel<<<NBLK_IP + NE / 256, 256, 0, stream>>>(
        src, dst, ew, rank, row_ptr, sEdge, X, WinT, b_in, hbf, PWT, P);

    const int nblk = (NN + 63) / 64;
    for (int l = 0; l < NL; ++l) {
        edge_csr_kernel<<<(NN * 64 + 255) / 256, 256, 0, stream>>>(
            P, sEdge, row_ptr,
            eW1 + (size_t)l * 257 * 128 + 256 * 128,
            eb1 + (size_t)l * D, Sbf);
        const u16* pwt_next = (l < NL - 1) ? (PWT + (size_t)(l + 1) * 256 * 128) : nullptr;
        node_mfma_kernel<<<nblk, 256, 0, stream>>>(
            hbf, Sbf, hist,
            NW1T + (size_t)l * 128 * 256, ub1 + (size_t)l * D, nb2p + (size_t)l * D,
            uW2T + (size_t)l * 128 * 128, ub2 + (size_t)l * D,
            gamma + (size_t)l * D, beta + (size_t)l * D,
            out_hidden, hbf, pwt_next, P, (l == NL - 1) ? 1 : 0,
            batch, out_pooled);
    }

    pool_div_kernel<<<(NG * D) / 256, 256, 0, stream>>>(out_pooled, counts);
}

// Round 15
// 411.140 us; speedup vs baseline: 1.0364x; 1.0364x over previous
//
#include <hip/hip_runtime.h>
#include <math.h>

#define NN 50000
#define NE 800000
#define DIN 32
#define D 128
#define NL 3
#define NG 64
#define LN_EPS 1e-5f
#define SCAN_BLOCKS 196   // ceil(NN/256)

// fused-prep grid layout
#define PR_T   48             // transpose: 4 regions x 3 layers x 4 tiles(64x64)
#define PR_W2P (PR_T + 192)   // w2p
#define PR_B2P (PR_W2P + 2)   // b2p (384 threads)
#define PR_WIN (PR_B2P + 16)  // winT
#define PR_CNT (PR_WIN + 32)  // count
#define PR_TOTAL (PR_CNT + NE / 256)   // + hist: 3415

#define NBLK_IP 782           // input_proj blocks in fused scatter+inproj

typedef unsigned short u16;
typedef __bf16 bf16x8 __attribute__((ext_vector_type(8)));
typedef float f32x4 __attribute__((ext_vector_type(4)));

// exact gelu (erf) — REQUIRED on the hidden path: replacing it with the
// tanh-approx tripled final absmax (round-5: 0.0625 -> 0.1875, fail).
__device__ __forceinline__ float gelu_f(float x) {
    return 0.5f * x * (1.0f + erff(x * 0.70710678118654752f));
}

// tanh-approx gelu: ONLY for edge messages (baseline-proven at absmax 0.0625).
__device__ __forceinline__ float gelu_fast(float x) {
    float u = x * x;
    float z = x * fmaf(-0.1029432f, u, -2.3022082f);
    float e = __builtin_amdgcn_exp2f(z);
    float s = __builtin_amdgcn_rcpf(1.0f + e);
    return x * s;
}

__device__ __forceinline__ u16 f2bf(float x) {
    unsigned int u = __float_as_uint(x);
    u += 0x7fffu + ((u >> 16) & 1u);
    return (u16)(u >> 16);
}

// ---------------- single-pass CSR scan ----------------
__global__ __launch_bounds__(256) void scan_emit_kernel(
    const int* __restrict__ hist, int* __restrict__ row_ptr)
{
    __shared__ int sc[256];
    __shared__ int red[256];
    const int t = threadIdx.x;
    const int blk = blockIdx.x;
    const int i = blk * 256 + t;
    int orig = (i < NN) ? hist[i] : 0;
    sc[t] = orig;

    int seg = 0;
    if (t < blk) {
        const int4* hp = (const int4*)(hist + t * 256);
#pragma unroll 8
        for (int m = 0; m < 64; ++m) {
            int4 v = hp[m];
            seg += v.x + v.y + v.z + v.w;
        }
    }
    red[t] = seg;
    __syncthreads();
    for (int off = 128; off > 0; off >>= 1) {
        if (t < off) red[t] += red[t + off];
        __syncthreads();
    }
    for (int off = 1; off < 256; off <<= 1) {
        int v = (t >= off) ? sc[t - off] : 0;
        __syncthreads();
        sc[t] += v;
        __syncthreads();
    }
    if (i < NN) row_ptr[i] = sc[t] - orig + red[0];
    if (i == 0) row_ptr[NN] = NE;
}

// ---------------- fused prep ----------------
__global__ __launch_bounds__(256) void prep_kernel(
    const float* __restrict__ eW1, const float* __restrict__ uW1,
    const float* __restrict__ uW2, const float* __restrict__ eW2,
    const float* __restrict__ eb2, const float* __restrict__ Wi,
    const int* __restrict__ batch, const int* __restrict__ dst,
    u16* __restrict__ PWT, u16* __restrict__ NW1T, u16* __restrict__ uW2T,
    float* __restrict__ nb2p, u16* __restrict__ WinT,
    float* __restrict__ counts, int* __restrict__ hist,
    int* __restrict__ rank)
{
    __shared__ __attribute__((aligned(16))) float ldsF[64 * 65];  // 16.6 KB
    const int blk = blockIdx.x;
    const int tid = threadIdx.x;
    if (blk < PR_T) {
        const int region = blk / 12;
        const int rl = blk - region * 12;
        const int l = rl >> 2;
        const int tile = rl & 3;
        const int k0 = (tile >> 1) * 64, n0 = (tile & 1) * 64;
        const float* srcp; u16* dstp; int dstRS;
        if (region == 0)      { srcp = eW1 + (size_t)l * 257 * 128;         dstp = PWT  + (size_t)l * 32768;         dstRS = 128; }
        else if (region == 1) { srcp = eW1 + (size_t)l * 257 * 128 + 16384; dstp = PWT  + (size_t)l * 32768 + 16384; dstRS = 128; }
        else if (region == 2) { srcp = uW1 + (size_t)l * 32768;             dstp = NW1T + (size_t)l * 32768;         dstRS = 256; }
        else                  { srcp = uW2 + (size_t)l * 16384;             dstp = uW2T + (size_t)l * 16384;         dstRS = 128; }
        const int rr = tid >> 6, cc = tid & 63;
#pragma unroll
        for (int it = 0; it < 16; ++it) {
            int row = it * 4 + rr;
            ldsF[row * 65 + cc] = srcp[(size_t)(k0 + row) * 128 + n0 + cc];
        }
        __syncthreads();
#pragma unroll
        for (int it = 0; it < 16; ++it) {
            int row = it * 4 + rr;
            dstp[(size_t)(n0 + row) * dstRS + k0 + cc] = f2bf(ldsF[cc * 65 + row]);
        }
    } else if (blk < PR_W2P) {
        int i = (blk - PR_T) * 256 + tid;
        int l = i / 16384;
        int r = i - l * 16384;
        int k = r >> 7, n = r & 127;
        const float* w2row = eW2 + (size_t)l * 16384 + k * 128;
        const float* u1col = uW1 + (size_t)l * 32768 + 128 * 128 + n;
        float s = 0.f;
#pragma unroll 4
        for (int j = 0; j < 128; ++j) s = fmaf(w2row[j], u1col[j * 128], s);
        NW1T[(size_t)l * 32768 + n * 256 + 128 + k] = f2bf(s);
    } else if (blk < PR_B2P) {
        int i = (blk - PR_W2P) * 256 + tid;
        if (i < NL * 128) {
            int l = i >> 7, n = i & 127;
            const float* b2r = eb2 + l * 128;
            const float* u1col = uW1 + (size_t)l * 32768 + 128 * 128 + n;
            float s = 0.f;
#pragma unroll 4
            for (int j = 0; j < 128; ++j) s = fmaf(b2r[j], u1col[j * 128], s);
            nb2p[l * 128 + n] = s;
        }
    } else if (blk < PR_WIN) {
        int i = (blk - PR_B2P) * 256 + tid;
        int n = i >> 5, k = i & 31;
        WinT[n * 32 + k] = f2bf(Wi[k * 128 + n]);
    } else if (blk < PR_CNT) {
        float* s_counts = ldsF;
        if (tid < NG) s_counts[tid] = 0.f;
        __syncthreads();
        int t = (blk - PR_WIN) * 256 + tid;
        const int chunk = (NN + 8191) / 8192;
        int beg = t * chunk, end = beg + chunk;
        if (end > NN) end = NN;
        if (beg < NN) {
            int cur = batch[beg];
            float cnt = 0.f;
            for (int i2 = beg; i2 < end; ++i2) {
                int b2 = batch[i2];
                if (b2 != cur) { atomicAdd(&s_counts[cur], cnt); cur = b2; cnt = 0.f; }
                cnt += 1.f;
            }
            atomicAdd(&s_counts[cur], cnt);
        }
        __syncthreads();
        if (tid < NG) {
            float v = s_counts[tid];
            if (v != 0.f) atomicAdd(&counts[tid], v);
        }
    } else {
        int e = (blk - PR_CNT) * 256 + tid;
        rank[e] = atomicAdd(&hist[dst[e]], 1);   // rank = old count
    }
}

// ---------------- fused scatter + input_proj -------------------------------
__global__ __launch_bounds__(256) void scatter_inproj_kernel(
    const int* __restrict__ src, const int* __restrict__ dstp,
    const float* __restrict__ ew, const int* __restrict__ rank,
    const int* __restrict__ row_ptr, int2* __restrict__ sEdge,
    const float* __restrict__ X, const u16* __restrict__ WinT,
    const float* __restrict__ b, u16* __restrict__ hbf,
    const u16* __restrict__ PWT, u16* __restrict__ P)
{
    __shared__ __attribute__((aligned(16))) u16 lds[64 * 264];  // 33792 B
    const int blk = blockIdx.x;
    const int tid = threadIdx.x;

    if (blk >= NBLK_IP) {   // ---- scatter region (no atomics) ----
        int e = (blk - NBLK_IP) * 256 + tid;
        int d = dstp[e];
        int pos = row_ptr[d] + rank[e];
        int2 v;
        v.x = src[e] << 9;            // row offset in bytes into P
        v.y = __float_as_int(ew[e]);
        sEdge[pos] = v;
        return;
    }

    // ---- input_proj region ----
    u16* sO  = lds;              // 64 x 136 bf16 hidden stage
    u16* sXb = lds + 64 * 136;   // 64 x 72 bf16 X stage: [hi(32) | lo(32) | pad]
    const int n0 = blk * 64;
    const int e = tid >> 2, q = tid & 3;

    {   // stage X -> hi/lo bf16 split (x = hi + lo recovers f32 precision)
        const int n = n0 + e;
        unsigned hiw[4], low[4];
        if (n < NN) {
            const float4* xr = (const float4*)(X + (size_t)n * DIN + q * 8);
            float vv[8];
            *(float4*)(vv) = xr[0];
            *(float4*)(vv + 4) = xr[1];
#pragma unroll
            for (int j = 0; j < 4; ++j) {
                u16 h0 = f2bf(vv[2 * j]), h1 = f2bf(vv[2 * j + 1]);
                float f0 = __uint_as_float((unsigned)h0 << 16);
                float f1 = __uint_as_float((unsigned)h1 << 16);
                u16 l0 = f2bf(vv[2 * j] - f0), l1 = f2bf(vv[2 * j + 1] - f1);
                hiw[j] = (unsigned)h0 | ((unsigned)h1 << 16);
                low[j] = (unsigned)l0 | ((unsigned)l1 << 16);
            }
        } else {
#pragma unroll
            for (int j = 0; j < 4; ++j) { hiw[j] = 0u; low[j] = 0u; }
        }
        *(uint4*)(sXb + e * 72 + q * 8)      = *(uint4*)hiw;
        *(uint4*)(sXb + e * 72 + 32 + q * 8) = *(uint4*)low;
    }
    __syncthreads();

    const int lane = tid & 63;
    const int l15 = lane & 15;
    const int quad = lane >> 4;
    const int w = tid >> 6;          // wave id: owns cols w*32..w*32+31

    {   // in-proj MFMA (2 accumulating K-steps: hi then lo), bias + exact gelu
        f32x4 acc1[4][2];
#pragma unroll
        for (int mt = 0; mt < 4; ++mt)
#pragma unroll
            for (int nt = 0; nt < 2; ++nt) acc1[mt][nt] = (f32x4){0.f, 0.f, 0.f, 0.f};

        bf16x8 bfw[2];
#pragma unroll
        for (int nt = 0; nt < 2; ++nt)
            bfw[nt] = *(const bf16x8*)(WinT + (size_t)(w * 32 + nt * 16 + l15) * 32 + quad * 8);
#pragma unroll
        for (int mt = 0; mt < 4; ++mt) {
            bf16x8 ah = *(const bf16x8*)(sXb + (mt * 16 + l15) * 72 + quad * 8);
            bf16x8 al = *(const bf16x8*)(sXb + (mt * 16 + l15) * 72 + 32 + quad * 8);
            acc1[mt][0] = __builtin_amdgcn_mfma_f32_16x16x32_bf16(ah, bfw[0], acc1[mt][0], 0, 0, 0);
            acc1[mt][0] = __builtin_amdgcn_mfma_f32_16x16x32_bf16(al, bfw[0], acc1[mt][0], 0, 0, 0);
            acc1[mt][1] = __builtin_amdgcn_mfma_f32_16x16x32_bf16(ah, bfw[1], acc1[mt][1], 0, 0, 0);
            acc1[mt][1] = __builtin_amdgcn_mfma_f32_16x16x32_bf16(al, bfw[1], acc1[mt][1], 0, 0, 0);
        }
#pragma unroll
        for (int mt = 0; mt < 4; ++mt)
#pragma unroll
            for (int nt = 0; nt < 2; ++nt) {
                const int col = w * 32 + nt * 16 + l15;
                const float bb = b[col];
#pragma unroll
                for (int r = 0; r < 4; ++r) {
                    const int row = mt * 16 + quad * 4 + r;
                    sO[row * 136 + col] = f2bf(gelu_f(acc1[mt][nt][r] + bb));
                }
            }
    }
    __syncthreads();   // sO complete, visible to all waves

    // hbf store
    {
        const int n = n0 + e;
        if (n < NN) {
            uint4* hp = (uint4*)(hbf + (size_t)n * D);
            const u16* so = sO + e * 136;
#pragma unroll
            for (int c = 0; c < 4; ++c) hp[q + c * 4] = *(const uint4*)(so + (q + c * 4) * 8);
        }
    }

    // layer-0 P-GEMM: P[n][0:256] = hidden[n] @ [W1a|W1b]
    const int nbase4 = w * 64;

    f32x4 accp[4][4];
#pragma unroll
    for (int mt = 0; mt < 4; ++mt)
#pragma unroll
        for (int nt = 0; nt < 4; ++nt) accp[mt][nt] = (f32x4){0.f, 0.f, 0.f, 0.f};

#pragma unroll
    for (int kb = 0; kb < 128; kb += 32) {
        bf16x8 bf[4];
#pragma unroll
        for (int nt = 0; nt < 4; ++nt)
            bf[nt] = *(const bf16x8*)(PWT + (size_t)(nbase4 + nt * 16 + l15) * 128 + quad * 8 + kb);
#pragma unroll
        for (int mt = 0; mt < 4; ++mt) {
            bf16x8 af = *(const bf16x8*)(sO + (mt * 16 + l15) * 136 + quad * 8 + kb);
#pragma unroll
            for (int nt = 0; nt < 4; ++nt)
                accp[mt][nt] = __builtin_amdgcn_mfma_f32_16x16x32_bf16(af, bf[nt], accp[mt][nt], 0, 0, 0);
        }
    }
    __syncthreads();   // all sO reads done -> reuse as sP

    u16* sP = lds;     // 64 x 264 u16
#pragma unroll
    for (int mt = 0; mt < 4; ++mt)
#pragma unroll
        for (int nt = 0; nt < 4; ++nt) {
            const int col = nbase4 + nt * 16 + l15;
#pragma unroll
            for (int r = 0; r < 4; ++r)
                sP[(mt * 16 + quad * 4 + r) * 264 + col] = f2bf(accp[mt][nt][r]);
        }
    __syncthreads();
    {
        const int n = n0 + e;
        if (n < NN) {
            uint4* op = (uint4*)(P + (size_t)n * 256);
            const u16* sp = sP + e * 264;
#pragma unroll
            for (int c = 0; c < 8; ++c) op[q + c * 4] = *(const uint4*)(sp + (q + c * 4) * 8);
        }
    }
}

// CSR edge pass: one wave per dst node, lane owns 2 cols. Zero atomics.
// Round-15: round-12's proven 4-gather load structure restored (the round-14
// 8-batch arrays forced coarse waitcnt groups and doubled VGPR -> +4.5us).
// Minimal controlled change: 2-way split accumulators (a-chain: gathers 0,2;
// b-chain: 1,3) halves the serial add chain at +2 VGPR, loads untouched.
__global__ __launch_bounds__(256) void edge_csr_kernel(
    const u16* __restrict__ P, const int2* __restrict__ sEdge,
    const int* __restrict__ row_ptr,
    const float* __restrict__ W1last, const float* __restrict__ b1,
    u16* __restrict__ Sbf)
{
    const int n = (blockIdx.x * 256 + threadIdx.x) >> 6;
    if (n >= NN) return;
    const int lane = threadIdx.x & 63;
    const int c2 = lane * 2;
    const unsigned laneoff = (unsigned)(c2 * 2);   // byte offset of this lane's dword in a P row
    const char* Pb = (const char*)P;

    const float wl0 = W1last[c2], wl1 = W1last[c2 + 1];
    unsigned p2 = *(const unsigned*)(Pb + ((unsigned)n * 512u + 256u + laneoff));
    const float t20 = __uint_as_float(p2 << 16) + b1[c2];
    const float t21 = __uint_as_float(p2 & 0xffff0000u) + b1[c2 + 1];

    float a0 = 0.f, a1 = 0.f;
    float e0 = 0.f, e1 = 0.f;
    const int beg = row_ptr[n];
    const int m = row_ptr[n + 1] - beg;
    const int2* ep = sEdge + beg;
    int i = 0;
    for (; i + 3 < m; i += 4) {            // 4 gathers in flight (round-12 form)
        int2 q0 = ep[i], q1 = ep[i + 1], q2 = ep[i + 2], q3 = ep[i + 3];
        unsigned pa = *(const unsigned*)(Pb + ((unsigned)q0.x + laneoff));
        unsigned pb = *(const unsigned*)(Pb + ((unsigned)q1.x + laneoff));
        unsigned pc = *(const unsigned*)(Pb + ((unsigned)q2.x + laneoff));
        unsigned pd = *(const unsigned*)(Pb + ((unsigned)q3.x + laneoff));
        float w0 = __int_as_float(q0.y), w1 = __int_as_float(q1.y);
        float w2 = __int_as_float(q2.y), w3 = __int_as_float(q3.y);
        a0 += gelu_fast(fmaf(w0, wl0, __uint_as_float(pa << 16) + t20));
        a1 += gelu_fast(fmaf(w0, wl1, __uint_as_float(pa & 0xffff0000u) + t21));
        e0 += gelu_fast(fmaf(w1, wl0, __uint_as_float(pb << 16) + t20));
        e1 += gelu_fast(fmaf(w1, wl1, __uint_as_float(pb & 0xffff0000u) + t21));
        a0 += gelu_fast(fmaf(w2, wl0, __uint_as_float(pc << 16) + t20));
        a1 += gelu_fast(fmaf(w2, wl1, __uint_as_float(pc & 0xffff0000u) + t21));
        e0 += gelu_fast(fmaf(w3, wl0, __uint_as_float(pd << 16) + t20));
        e1 += gelu_fast(fmaf(w3, wl1, __uint_as_float(pd & 0xffff0000u) + t21));
    }
    for (; i < m; ++i) {
        int2 q0 = ep[i];
        unsigned pa = *(const unsigned*)(Pb + ((unsigned)q0.x + laneoff));
        float w0 = __int_as_float(q0.y);
        a0 += gelu_fast(fmaf(w0, wl0, __uint_as_float(pa << 16) + t20));
        a1 += gelu_fast(fmaf(w0, wl1, __uint_as_float(pa & 0xffff0000u) + t21));
    }
    a0 += e0;
    a1 += e1;
    unsigned pk = (unsigned)f2bf(a0) | ((unsigned)f2bf(a1) << 16);
    *(unsigned*)(Sbf + (size_t)n * D + c2) = pk;
}

// Node update on MFMA + residual + LayerNorm; two-pass next-layer P-GEMM
// (round-11: keeps regs under the (256,4) cap -> single co-residency round);
// fused pooling accumulation on the last layer (write_f32).
__global__ __launch_bounds__(256, 4) void node_mfma_kernel(
    const u16* __restrict__ hbf, const u16* __restrict__ Sbf,
    const int* __restrict__ hist,
    const u16* __restrict__ NW1T, const float* __restrict__ ub1,
    const float* __restrict__ nb2p,
    const u16* __restrict__ W2T, const float* __restrict__ b2,
    const float* __restrict__ gamma, const float* __restrict__ beta,
    float* __restrict__ hidden_out, u16* __restrict__ hbf_out,
    const u16* __restrict__ PWTnext, u16* __restrict__ Pout, int write_f32,
    const int* __restrict__ batch, float* __restrict__ pooled)
{
    __shared__ __attribute__((aligned(16))) u16 ldsA[64 * 136 * 2];  // 34816 B
    __shared__ float s_cnt[64];
    __shared__ int s_b[64];
    u16* sHa = ldsA;               // 64x136: hbf rows (live until residual)
    u16* sSb = ldsA + 64 * 136;    // 64x136: Sbf rows, then H1 (gelu out)
    float* sR = (float*)ldsA;      // 64x132 f32 LN buffer (reuses all)
    const int tid = threadIdx.x;
    const int n0 = blockIdx.x * 64;

    if (tid < 64) {
        int n = n0 + tid;
        s_b[tid] = (write_f32 && n < NN) ? batch[n] : -1;
        if (n >= NN) n = NN - 1;
        s_cnt[tid] = (float)hist[n];
    }
    {
        const int e = tid >> 2, q = tid & 3;
        int n = n0 + e; if (n >= NN) n = NN - 1;
        const uint4* hs = (const uint4*)(hbf + (size_t)n * D);
        const uint4* ss = (const uint4*)(Sbf + (size_t)n * D);
#pragma unroll
        for (int j = 0; j < 4; ++j) {          // full 128-u16 row per buffer
            const int c = q * 4 + j;
            *(uint4*)(sHa + e * 136 + c * 8) = hs[c];
            *(uint4*)(sSb + e * 136 + c * 8) = ss[c];
        }
    }
    __syncthreads();

    const int lane = tid & 63;
    const int l15 = lane & 15;
    const int quad = lane >> 4;
    const int nbase = (tid >> 6) * 32;

    f32x4 acc[4][2];
#pragma unroll
    for (int mt = 0; mt < 4; ++mt)
#pragma unroll
        for (int nt = 0; nt < 2; ++nt) acc[mt][nt] = (f32x4){0.f, 0.f, 0.f, 0.f};

    const u16* bp0 = NW1T + (size_t)(nbase + l15) * 256 + quad * 8;
    const u16* bp1 = bp0 + 16 * 256;
#pragma unroll
    for (int kb = 0; kb < 256; kb += 32) {
        bf16x8 bf0 = *(const bf16x8*)(bp0 + kb);
        bf16x8 bf1 = *(const bf16x8*)(bp1 + kb);
        const u16* abase = (kb < 128) ? sHa : sSb;   // compile-time under unroll
        const int kk = kb & 127;
#pragma unroll
        for (int mt = 0; mt < 4; ++mt) {
            bf16x8 af = *(const bf16x8*)(abase + (mt * 16 + l15) * 136 + quad * 8 + kk);
            acc[mt][0] = __builtin_amdgcn_mfma_f32_16x16x32_bf16(af, bf0, acc[mt][0], 0, 0, 0);
            acc[mt][1] = __builtin_amdgcn_mfma_f32_16x16x32_bf16(af, bf1, acc[mt][1], 0, 0, 0);
        }
    }
    __syncthreads();   // all GEMM1 A-reads done; sSb becomes H1

#pragma unroll
    for (int mt = 0; mt < 4; ++mt)
#pragma unroll
        for (int nt = 0; nt < 2; ++nt) {
            const int col = nbase + nt * 16 + l15;
            const float bb = ub1[col];
            const float bp = nb2p[col];
#pragma unroll
            for (int r = 0; r < 4; ++r) {
                const int row = mt * 16 + quad * 4 + r;
                float v = acc[mt][nt][r] + bb + s_cnt[row] * bp;
                sSb[row * 136 + col] = f2bf(gelu_f(v));
            }
        }
    __syncthreads();

    f32x4 acc2[4][2];
#pragma unroll
    for (int mt = 0; mt < 4; ++mt)
#pragma unroll
        for (int nt = 0; nt < 2; ++nt) acc2[mt][nt] = (f32x4){0.f, 0.f, 0.f, 0.f};

    const u16* cp0 = W2T + (size_t)(nbase + l15) * 128 + quad * 8;
    const u16* cp1 = cp0 + 16 * 128;
#pragma unroll
    for (int kb = 0; kb < 128; kb += 32) {
        bf16x8 bf0 = *(const bf16x8*)(cp0 + kb);
        bf16x8 bf1 = *(const bf16x8*)(cp1 + kb);
#pragma unroll
        for (int mt = 0; mt < 4; ++mt) {
            bf16x8 af = *(const bf16x8*)(sSb + (mt * 16 + l15) * 136 + quad * 8 + kb);
            acc2[mt][0] = __builtin_amdgcn_mfma_f32_16x16x32_bf16(af, bf0, acc2[mt][0], 0, 0, 0);
            acc2[mt][1] = __builtin_amdgcn_mfma_f32_16x16x32_bf16(af, bf1, acc2[mt][1], 0, 0, 0);
        }
    }

    // bias + residual from LDS (sHa still intact)
#pragma unroll
    for (int mt = 0; mt < 4; ++mt)
#pragma unroll
        for (int nt = 0; nt < 2; ++nt) {
            const int col = nbase + nt * 16 + l15;
            const float bb = b2[col];
#pragma unroll
            for (int r = 0; r < 4; ++r) {
                const int row = mt * 16 + quad * 4 + r;
                float h = __uint_as_float((unsigned)sHa[row * 136 + col] << 16);
                acc2[mt][nt][r] += bb + h;
            }
        }
    __syncthreads();   // all reads of ldsA done; overwrite with f32 sR

#pragma unroll
    for (int mt = 0; mt < 4; ++mt)
#pragma unroll
        for (int nt = 0; nt < 2; ++nt) {
            const int col = nbase + nt * 16 + l15;
#pragma unroll
            for (int r = 0; r < 4; ++r)
                sR[(mt * 16 + quad * 4 + r) * 132 + col] = acc2[mt][nt][r];
        }
    __syncthreads();

    // LayerNorm: 4 lanes per row (same wave). bf16 written in place (safe:
    // data dependence on rs orders all row reads before any store).
    {
        const int e = tid >> 2, t4 = tid & 3;
        float* rr = sR + e * 132 + t4 * 32;
        float s1 = 0.f, s2 = 0.f;
        float4 v[8];
#pragma unroll
        for (int i = 0; i < 8; ++i) {
            v[i] = *(const float4*)(rr + i * 4);
            s1 += v[i].x + v[i].y + v[i].z + v[i].w;
            s2 += v[i].x * v[i].x + v[i].y * v[i].y + v[i].z * v[i].z + v[i].w * v[i].w;
        }
        s1 += __shfl_xor(s1, 1); s2 += __shfl_xor(s2, 1);
        s1 += __shfl_xor(s1, 2); s2 += __shfl_xor(s2, 2);
        const float mean = s1 * (1.f / 128.f);
        const float var = s2 * (1.f / 128.f) - mean * mean;
        const float rs = rsqrtf(var + LN_EPS);
        u16* hrow = (u16*)(sR + e * 132);   // bf16 row, stride 264 u16
#pragma unroll
        for (int i = 0; i < 8; ++i) {
            const float4 g = *(const float4*)(gamma + t4 * 32 + i * 4);
            const float4 be = *(const float4*)(beta + t4 * 32 + i * 4);
            float4 o;
            o.x = (v[i].x - mean) * rs * g.x + be.x;
            o.y = (v[i].y - mean) * rs * g.y + be.y;
            o.z = (v[i].z - mean) * rs * g.z + be.z;
            o.w = (v[i].w - mean) * rs * g.w + be.w;
            if (write_f32) {
                *(float4*)(rr + i * 4) = o;
            } else {
                uint2 pk;
                pk.x = (unsigned)f2bf(o.x) | ((unsigned)f2bf(o.y) << 16);
                pk.y = (unsigned)f2bf(o.z) | ((unsigned)f2bf(o.w) << 16);
                *(uint2*)(hrow + t4 * 32 + i * 4) = pk;
            }
        }
    }

    if (write_f32) {
        __syncthreads();   // pooled reads cross-wave rows
        {
            const int e = tid >> 2, q = tid & 3;
            const int n = n0 + e;
            if (n < NN) {
                float4* op = (float4*)(hidden_out + (size_t)n * D);
                const float* sr = sR + e * 132;
#pragma unroll
                for (int c = 0; c < 8; ++c) op[q + c * 4] = *(const float4*)(sr + (q + c * 4) * 4);
            }
        }
        {
            const int col = tid & 127, half = tid >> 7;
            const int base = half * 32;
            int cur = s_b[base];
            float acc_p = 0.f;
            for (int i = 0; i < 32; ++i) {
                int b = s_b[base + i];
                if (b < 0) break;
                if (b != cur) { atomicAdd(&pooled[cur * D + col], acc_p); cur = b; acc_p = 0.f; }
                acc_p += sR[(base + i) * 132 + col];
            }
            if (cur >= 0) atomicAdd(&pooled[cur * D + col], acc_p);
        }
    } else {
        __syncthreads();   // LN bf16 rows visible to all waves
        {
            const int e = tid >> 2, q = tid & 3;
            const int n = n0 + e;
            if (n < NN) {
                uint4* hp = (uint4*)(hbf_out + (size_t)n * D);
                const u16* sh = (const u16*)(sR + e * 132);
#pragma unroll
                for (int c = 0; c < 4; ++c) hp[q + c * 4] = *(const uint4*)(sh + (q + c * 4) * 8);
            }
        }
        if (PWTnext) {
            // two-pass P-GEMM (accp[4][2] each) keeps regs under the (256,4)
            // cap. sHn = bf16 LN rows, stride 264, cols [0,128).
            const u16* sHn = (const u16*)sR;
            u16* sPx = (u16*)sR;               // staging within sR rows
            const int cbase = (tid >> 6) * 32; // wave's 32-col slice per pass
            f32x4 accp[4][2];

            // ---- pass A: P cols [0,128) -> stage at row*264 + 128 + col ----
#pragma unroll
            for (int mt = 0; mt < 4; ++mt)
#pragma unroll
                for (int nt = 0; nt < 2; ++nt) accp[mt][nt] = (f32x4){0.f, 0.f, 0.f, 0.f};
#pragma unroll
            for (int kb = 0; kb < 128; kb += 32) {
                bf16x8 bf0 = *(const bf16x8*)(PWTnext + (size_t)(cbase + l15) * 128 + quad * 8 + kb);
                bf16x8 bf1 = *(const bf16x8*)(PWTnext + (size_t)(cbase + 16 + l15) * 128 + quad * 8 + kb);
#pragma unroll
                for (int mt = 0; mt < 4; ++mt) {
                    bf16x8 af = *(const bf16x8*)(sHn + (size_t)(mt * 16 + l15) * 264 + quad * 8 + kb);
                    accp[mt][0] = __builtin_amdgcn_mfma_f32_16x16x32_bf16(af, bf0, accp[mt][0], 0, 0, 0);
                    accp[mt][1] = __builtin_amdgcn_mfma_f32_16x16x32_bf16(af, bf1, accp[mt][1], 0, 0, 0);
                }
            }
#pragma unroll
            for (int mt = 0; mt < 4; ++mt)
#pragma unroll
                for (int nt = 0; nt < 2; ++nt) {
                    const int col = cbase + nt * 16 + l15;
#pragma unroll
                    for (int r = 0; r < 4; ++r)
                        sPx[(mt * 16 + quad * 4 + r) * 264 + 128 + col] = f2bf(accp[mt][nt][r]);
                }

            // ---- pass B: P cols [128,256) ----
#pragma unroll
            for (int mt = 0; mt < 4; ++mt)
#pragma unroll
                for (int nt = 0; nt < 2; ++nt) accp[mt][nt] = (f32x4){0.f, 0.f, 0.f, 0.f};
#pragma unroll
            for (int kb = 0; kb < 128; kb += 32) {
                bf16x8 bf0 = *(const bf16x8*)(PWTnext + (size_t)(128 + cbase + l15) * 128 + quad * 8 + kb);
                bf16x8 bf1 = *(const bf16x8*)(PWTnext + (size_t)(128 + cbase + 16 + l15) * 128 + quad * 8 + kb);
#pragma unroll
                for (int mt = 0; mt < 4; ++mt) {
                    bf16x8 af = *(const bf16x8*)(sHn + (size_t)(mt * 16 + l15) * 264 + quad * 8 + kb);
                    accp[mt][0] = __builtin_amdgcn_mfma_f32_16x16x32_bf16(af, bf0, accp[mt][0], 0, 0, 0);
                    accp[mt][1] = __builtin_amdgcn_mfma_f32_16x16x32_bf16(af, bf1, accp[mt][1], 0, 0, 0);
                }
            }
            __syncthreads();   // all sHn reads done -> overwrite cols [0,128)
#pragma unroll
            for (int mt = 0; mt < 4; ++mt)
#pragma unroll
                for (int nt = 0; nt < 2; ++nt) {
                    const int col = cbase + nt * 16 + l15;   // = B col - 128
#pragma unroll
                    for (int r = 0; r < 4; ++r)
                        sPx[(mt * 16 + quad * 4 + r) * 264 + col] = f2bf(accp[mt][nt][r]);
                }
            __syncthreads();
            // coalesced store: P[n][0:128) from +128 tail, P[n][128:256) from +0
            const int e2 = tid >> 2, q2 = tid & 3;
            const int n2 = n0 + e2;
            if (n2 < NN) {
                uint4* op = (uint4*)(Pout + (size_t)n2 * 256);
                const u16* rowp = sPx + e2 * 264;
#pragma unroll
                for (int c = 0; c < 4; ++c)
                    op[q2 + c * 4] = *(const uint4*)(rowp + 128 + (q2 + c * 4) * 8);
#pragma unroll
                for (int c = 0; c < 4; ++c)
                    op[16 + q2 + c * 4] = *(const uint4*)(rowp + (q2 + c * 4) * 8);
            }
        }
    }
}

__global__ __launch_bounds__(256) void pool_div_kernel(
    float* __restrict__ pooled, const float* __restrict__ counts)
{
    int i = blockIdx.x * 256 + threadIdx.x;
    pooled[i] /= fmaxf(counts[i >> 7], 1.0f);
}

extern "C" void kernel_launch(void* const* d_in, const int* in_sizes, int n_in,
                              void* d_out, int out_size, void* d_ws, size_t ws_size,
                              hipStream_t stream) {
    const float* X     = (const float*)d_in[0];
    const int*   eidx  = (const int*)d_in[1];
    const float* ew    = (const float*)d_in[2];
    const int*   batch = (const int*)d_in[3];
    const float* W_in  = (const float*)d_in[5];
    const float* b_in  = (const float*)d_in[6];
    const float* eW1   = (const float*)d_in[7];
    const float* eb1   = (const float*)d_in[8];
    const float* eW2   = (const float*)d_in[9];
    const float* eb2   = (const float*)d_in[10];
    const float* uW1   = (const float*)d_in[11];
    const float* ub1   = (const float*)d_in[12];
    const float* uW2   = (const float*)d_in[13];
    const float* ub2   = (const float*)d_in[14];
    const float* gamma = (const float*)d_in[15];
    const float* beta  = (const float*)d_in[16];

    float* out_hidden = (float*)d_out;
    float* out_pooled = out_hidden + (size_t)NN * D;

    u16*   hbf  = (u16*)d_ws;                                  // N*128 bf16
    u16*   P    = hbf + (size_t)NN * D;                        // N*256 bf16
    u16*   Sbf  = P + (size_t)NN * 256;                        // N*128 bf16
    u16*   PWT  = Sbf + (size_t)NN * D;                        // NL*256*128
    u16*   NW1T = PWT + (size_t)NL * 256 * 128;                // NL*128*256
    u16*   uW2T = NW1T + (size_t)NL * 128 * 256;               // NL*128*128
    float* nb2p = (float*)(uW2T + (size_t)NL * 128 * 128);     // NL*128
    u16*   WinT = (u16*)(nb2p + (size_t)NL * 128);             // 128*32 bf16
    int*   hist    = (int*)(WinT + 128 * 32);
    int*   row_ptr = hist + NN;                                // NN+1 ints
    int2*  sEdge   = (int2*)(row_ptr + NN + 3);                // NE int2 (8B aligned)
    float* counts  = (float*)(sEdge + NE);
    int*   rank    = (int*)(counts + NG);                      // NE ints

    const int* src = eidx;
    const int* dst = eidx + NE;

    hipMemsetAsync(hist, 0, (size_t)NN * sizeof(int), stream);
    hipMemsetAsync(out_pooled, 0, (size_t)NG * D * sizeof(float), stream);
    hipMemsetAsync(counts, 0, (size_t)NG * sizeof(float), stream);

    // fused prep: transpose + w2p + b2p + winT + count + hist(+rank)
    prep_kernel<<<PR_TOTAL, 256, 0, stream>>>(
        eW1, uW1, uW2, eW2, eb2, W_in, batch, dst,
        PWT, NW1T, uW2T, nb2p, WinT, counts, hist, rank);

    // single-pass scan (replaces bsum + bscan + emit)
    scan_emit_kernel<<<SCAN_BLOCKS, 256, 0, stream>>>(hist, row_ptr);

    // fused scatter + input_proj (scatter is atomic-free via rank)
    scatter_inproj_kernel<<<NBLK_IP + NE / 256, 256, 0, stream>>>(
        src, dst, ew, rank, row_ptr, sEdge, X, WinT, b_in, hbf, PWT, P);

    const int nblk = (NN + 63) / 64;
    for (int l = 0; l < NL; ++l) {
        edge_csr_kernel<<<(NN * 64 + 255) / 256, 256, 0, stream>>>(
            P, sEdge, row_ptr,
            eW1 + (size_t)l * 257 * 128 + 256 * 128,
            eb1 + (size_t)l * D, Sbf);
        const u16* pwt_next = (l < NL - 1) ? (PWT + (size_t)(l + 1) * 256 * 128) : nullptr;
        node_mfma_kernel<<<nblk, 256, 0, stream>>>(
            hbf, Sbf, hist,
            NW1T + (size_t)l * 128 * 256, ub1 + (size_t)l * D, nb2p + (size_t)l * D,
            uW2T + (size_t)l * 128 * 128, ub2 + (size_t)l * D,
            gamma + (size_t)l * D, beta + (size_t)l * D,
            out_hidden, hbf, pwt_next, P, (l == NL - 1) ? 1 : 0,
            batch, out_pooled);
    }

    pool_div_kernel<<<(NG * D) / 256, 256, 0, stream>>>(out_pooled, counts);
}